// Round 10
// baseline (176.096 us; speedup 1.0000x reference)
//
#include <hip/hip_runtime.h>

#define B_ 4
#define N_ 2048
#define K_ 32
#define CIN_ 16
#define COUT_ 32
#define H_ 32
#define R_ (B_*N_*K_)      // 262144 rows through the weight-net
#define EPS_ 1e-5f
#define INVR_ (1.0f/(float)R_)
#define INVBN_ (1.0f/(float)(B_*N_))
#define LISTCAP 112
#define NSH 16             // stat shadows

typedef __attribute__((ext_vector_type(8)))  _Float16 f16x8;
typedef __attribute__((ext_vector_type(2)))  __fp16   hw16x2;   // builtin cvt_pkrtz return type
typedef __attribute__((ext_vector_type(2)))  _Float16 f16x2;
typedef __attribute__((ext_vector_type(16))) float    f32x16;

__device__ __forceinline__ float dot3f(float ax,float ay,float az,float bx,float by,float bz){
    return fmaf(az,bz, fmaf(ay,by, ax*bx));
}
__device__ __forceinline__ unsigned int pk2(float a, float b){   // packed f16 pair (RTZ)
    union { hw16x2 v; unsigned int u; } c;
    c.v = __builtin_amdgcn_cvt_pkrtz(a, b);
    return c.u;
}
__device__ __forceinline__ unsigned int pkmul(unsigned int a, unsigned int b){  // v_pk_mul_f16
    union { unsigned int u; f16x2 v; } x, y, r;
    x.u = a; y.u = b; r.v = x.v * y.v; return r.u;
}
// sum of NSH shadow accumulators
__device__ __forceinline__ float shsum(const float* __restrict__ p, int k){
    float s = 0.f;
    #pragma unroll
    for (int i = 0; i < NSH; ++i) s += p[i*32 + k];
    return s;
}

// ---- prep0: xs4g[b*N+n] = (x,y,z,|p|^2); zero stats ----
__global__ __launch_bounds__(256) void k_prep0(const float* __restrict__ xyz, float4* __restrict__ xs4g,
                                               float* __restrict__ st){
    int i = blockIdx.x*256 + threadIdx.x;      // 32 blocks x 256 = 8192
    float x = xyz[3*i], y = xyz[3*i+1], z = xyz[3*i+2];
    xs4g[i] = make_float4(x, y, z, dot3f(x,y,z,x,y,z));
    if (blockIdx.x == 0){
        for (int j = threadIdx.x; j < 1152; j += 256) st[j] = 0.f;
    }
}

// ---------------- KNN: 1 wave/query, wave-autonomous, single-pass linear-bucket histogram ----------------
// (256,6): round-9's (256,8) capped VGPR at 64 -> pass-1's 32 float4 loads lost MLP (dur 42->49).
__global__ __launch_bounds__(256,6) void k_knn(const float4* __restrict__ xs4g,
                                               const float* __restrict__ W1, const float* __restrict__ b1,
                                               int* __restrict__ idx_out,
                                               float* __restrict__ s1sh, float* __restrict__ q1sh){
    __shared__ unsigned int hist[4][512][2];          // 16 KB: per-wave 512 buckets x2 replicas
    __shared__ unsigned long long lst[4][LISTCAP];    // 3.5 KB
    __shared__ int kidx[4][K_];                       // 0.5 KB  -> 20 KB total, 8 blocks/CU

    const int tid  = threadIdx.x;
    const int w    = tid >> 6;
    const int lane = tid & 63;
    const int half = lane >> 5;
    const int b    = blockIdx.x >> 9;
    const int q    = ((blockIdx.x & 511) << 2) + w;
    const int bN   = b * N_;
    unsigned int* hw = &hist[w][0][0];

    const uint4 z4 = make_uint4(0,0,0,0);
    uint4* h4 = (uint4*)hw;                           // 256 uint4 per wave
    #pragma unroll
    for (int i = 0; i < 4; ++i) h4[i*64 + lane] = z4;

    const float4 qp = xs4g[bN + q];
    const float qx = qp.x, qy = qp.y, qz = qp.z, sqq = qp.w;

    // pass 1: 32 candidates/lane, cache d-bits, linear histogram
    unsigned int fv[32];
    #pragma unroll
    for (int j = 0; j < 32; ++j){
        int c = j*64 + lane;
        float4 pt = xs4g[bN + c];
        float d = fmaf(-2.0f, dot3f(qx,qy,qz, pt.x,pt.y,pt.z), sqq) + pt.w;
        fv[j] = __float_as_uint(d);
        unsigned int u1 = __float_as_uint(d + 1.0f);
        unsigned int key = (u1 <= 0x3F800000u) ? 0u : ((u1 - 0x3F800000u) >> 15);
        key = key > 511u ? 511u : key;
        atomicAdd(&hw[key*2 + (lane & 1)], 1u);
    }

    // select: smallest bucket with cumulative >= K (lane covers 8 buckets)
    unsigned int g[8];
    #pragma unroll
    for (int t = 0; t < 4; ++t){
        uint4 h = ((const uint4*)hw)[lane*4 + t];
        g[2*t]   = h.x + h.y;
        g[2*t+1] = h.z + h.w;
    }
    unsigned int gs = 0;
    #pragma unroll
    for (int t = 0; t < 8; ++t) gs += g[t];
    unsigned int cum = gs;
    #pragma unroll
    for (int off = 1; off < 64; off <<= 1){
        unsigned int v = __shfl_up(cum, off);
        if (lane >= off) cum += v;
    }
    unsigned long long bal = __ballot(cum >= (unsigned)K_);
    int L = __ffsll(bal) - 1;
    unsigned int run = __shfl(cum, L) - __shfl(gs, L);
    int Bsel = 8*L + 7;
    {
        unsigned int c = run; bool fnd = false;
        #pragma unroll
        for (int t = 0; t < 8; ++t){
            unsigned int ht = __shfl(g[t], L, 64);
            if (!fnd && c + ht >= (unsigned)K_){ Bsel = 8*L + t; fnd = true; }
            c += ht;
        }
    }
    const float Tedge = __uint_as_float(0x3F800000u + ((unsigned)(Bsel + 1) << 15));
    const bool allin = (Bsel == 511);

    // pass 2: ballot-compaction of survivors (f1 < Tedge <=> bucket <= Bsel)
    const unsigned long long mlt = (lane == 63) ? ~0ull >> 1 : (1ull << lane) - 1ull;
    unsigned int cnt = 0;
    #pragma unroll
    for (int j = 0; j < 32; ++j){
        float f1 = __uint_as_float(fv[j]) + 1.0f;
        bool surv = (f1 < Tedge) || allin;
        unsigned long long sb = __ballot(surv);
        unsigned int pos = cnt + (unsigned int)__popcll(sb & mlt);
        if (surv && pos < (unsigned)LISTCAP)
            lst[w][pos] = ((unsigned long long)fv[j] << 32) | (unsigned int)(j*64 + lane);
        cnt += (unsigned int)__popcll(sb);
    }
    int m = (int)cnt; if (m > LISTCAP) m = LISTCAP;

    // rank-select (keys unique: idx in low bits) -> exact top_k tie-break
    int* outp = idx_out + ((size_t)bN + q) * K_;
    for (int i = lane; i < m; i += 64){
        unsigned long long my = lst[w][i];
        int rank = 0;
        for (int jj = 0; jj < m; ++jj)
            rank += (lst[w][jj] < my) ? 1 : 0;
        if (rank < K_){
            int id = (int)(unsigned int)(my & 0xFFFFFFFFull);
            outp[rank] = id;
            kidx[w][rank] = id;
        }
    }

    // fused h1 stats: ch = lane&31; halves split the 32 neighbors (16 each)
    {
        const int ch = lane & 31;
        float w1a = W1[ch], w1b = W1[H_+ch], w1c = W1[2*H_+ch], b1c = b1[ch];
        float s = 0.f, qq = 0.f;
        #pragma unroll
        for (int r = 0; r < 16; ++r){
            int idr = kidx[w][half*16 + r];            // wave-uniform LDS broadcast
            float4 pn = xs4g[bN + idr];
            float rx = pn.x - qx, ry = pn.y - qy, rz = pn.z - qz;
            float h = fmaxf(fmaf(rx, w1a, fmaf(ry, w1b, fmaf(rz, w1c, b1c))), 0.0f);
            s += h; qq = fmaf(h, h, qq);
        }
        s  += __shfl_xor(s, 32, 64);
        qq += __shfl_xor(qq, 32, 64);
        if (lane < 32){
            int sh = (blockIdx.x & (NSH-1)) * 32 + ch;
            atomicAdd(&s1sh[sh], s);
            atomicAdd(&q1sh[sh], qq);
        }
    }
}

// ---------------- h1 (raw) from xs4g ----------------
__device__ __forceinline__ void compute_h1v(const float4* __restrict__ xs4g, const int* __restrict__ idx, int r,
                                            const float* __restrict__ W1, const float* __restrict__ b1, float* h1){
    int b = r >> 16;
    int n = (r >> 5) & (N_-1);
    int id = idx[r];
    float4 pc = xs4g[b*N_ + n];
    float4 pn = xs4g[b*N_ + id];
    float rx = pn.x - pc.x, ry = pn.y - pc.y, rz = pn.z - pc.z;
    #pragma unroll
    for (int j = 0; j < H_; ++j){
        float a = fmaf(rx, W1[j], fmaf(ry, W1[H_+j], fmaf(rz, W1[2*H_+j], b1[j])));
        h1[j] = fmaxf(a, 0.0f);
    }
}

// ---- prep2: points->f16 pairs; W2' = a1(.)W2 f16 frags; b2' = b2 + bb1@W2 (shadow-summed s1/q1) ----
__global__ __launch_bounds__(256) void k_prep2(const float* __restrict__ points,
                                               const float* __restrict__ s1s, const float* __restrict__ q1s,
                                               const float* __restrict__ g1, const float* __restrict__ be1,
                                               const float* __restrict__ W2, const float* __restrict__ b2,
                                               unsigned int* __restrict__ pf16, unsigned int* __restrict__ W2f,
                                               float* __restrict__ b2p){
    int flat = blockIdx.x*256 + threadIdx.x;
    if (flat < 65536){
        pf16[flat] = pk2(points[2*flat], points[2*flat+1]);
    } else if (flat < 66048){
        int d = flat - 65536;              // W2f dword index = (s*64+lane)*4+jj
        int jj = d & 3, lane = (d >> 2) & 63, s = d >> 8;
        int col = lane & 31;
        int k0 = s*16 + (lane >> 5)*8 + 2*jj;
        float m0 = shsum(s1s,k0)*INVR_,   v0 = shsum(q1s,k0)*INVR_   - m0*m0;
        float m1 = shsum(s1s,k0+1)*INVR_, v1 = shsum(q1s,k0+1)*INVR_ - m1*m1;
        float a0  = g1[k0]   / sqrtf(v0 + EPS_);
        float a1v = g1[k0+1] / sqrtf(v1 + EPS_);
        W2f[d] = pk2(a0*W2[k0*H_ + col], a1v*W2[(k0+1)*H_ + col]);
    } else if (flat < 66080){
        int col = flat - 66048;
        float acc = b2[col];
        #pragma unroll 4
        for (int h = 0; h < H_; ++h){
            float mm = shsum(s1s,h)*INVR_, vv = shsum(q1s,h)*INVR_ - mm*mm;
            float aa = g1[h] / sqrtf(vv + EPS_);
            float bb = fmaf(-aa, mm, be1[h]);
            acc = fmaf(bb, W2[h*H_ + col], acc);
        }
        b2p[col] = acc;
    }
}

// ---- k_h2stats: h1 -> layer2 MFMA (C[row][ch]) -> relu -> per-channel stats ONLY (no h2 store) ----
__global__ __launch_bounds__(256,4) void k_h2stats(const float4* __restrict__ xs4g, const int* __restrict__ idx,
                                                   const float* __restrict__ W1, const float* __restrict__ b1,
                                                   const uint4* __restrict__ W2f, const float* __restrict__ b2p,
                                                   float* gsum, float* gsq){
    __shared__ float redS[H_], redQ[H_];
    const int tid = threadIdx.x, lane = tid & 63, w = tid >> 6;
    const int half = lane >> 5, m = lane & 31;
    if (tid < H_){ redS[tid] = 0.f; redQ[tid] = 0.f; }
    __syncthreads();

    int r = blockIdx.x*256 + tid;
    float h1[H_];
    compute_h1v(xs4g, idx, r, W1, b1, h1);
    unsigned int h1p[16];
    #pragma unroll
    for (int i = 0; i < 16; ++i) h1p[i] = pk2(h1[2*i], h1[2*i+1]);

    union { uint4 u4; f16x8 v; } Bf0, Bf1;
    Bf0.u4 = W2f[lane];
    Bf1.u4 = W2f[64 + lane];
    float b2c = b2p[m];

    float s = 0.f, q = 0.f;
    #pragma unroll
    for (int t = 0; t < 2; ++t){
        const int src = t*32 + m;
        union { unsigned int u[4]; f16x8 v; } a0, a1f;
        #pragma unroll
        for (int jj = 0; jj < 4; ++jj){
            unsigned int lo = __shfl(h1p[jj],     src, 64);
            unsigned int hi = __shfl(h1p[4 + jj], src, 64);
            a0.u[jj] = half ? hi : lo;
        }
        #pragma unroll
        for (int jj = 0; jj < 4; ++jj){
            unsigned int lo = __shfl(h1p[8 + jj],  src, 64);
            unsigned int hi = __shfl(h1p[12 + jj], src, 64);
            a1f.u[jj] = half ? hi : lo;
        }
        f32x16 acc;
        #pragma unroll
        for (int i = 0; i < 16; ++i) acc[i] = b2c;
        acc = __builtin_amdgcn_mfma_f32_32x32x16_f16(a0.v,  Bf0.v, acc, 0, 0, 0);
        acc = __builtin_amdgcn_mfma_f32_32x32x16_f16(a1f.v, Bf1.v, acc, 0, 0, 0);
        #pragma unroll
        for (int i = 0; i < 16; ++i){
            float v = fmaxf(acc[i], 0.0f);
            s += v; q = fmaf(v, v, q);
        }
    }
    s += __shfl_xor(s, 32, 64);
    q += __shfl_xor(q, 32, 64);
    if (lane < 32){ atomicAdd(&redS[m], s); atomicAdd(&redQ[m], q); }
    __syncthreads();
    if (tid < H_){ atomicAdd(&gsum[tid], redS[tid]); atomicAdd(&gsq[tid], redQ[tid]); }
}

// ---- prep3: W3'' = aa2(.)W3 (+ b3' bias row at step 32) -> f16 B-frags for K=528 ----
__global__ __launch_bounds__(256) void k_prep3(const float* __restrict__ W3, const float* __restrict__ b3,
                                               const float* __restrict__ s2, const float* __restrict__ q2,
                                               const float* __restrict__ g2, const float* __restrict__ be2,
                                               unsigned int* __restrict__ W3f){
    int d = blockIdx.x*256 + threadIdx.x;     // 33*256 = 8448 dwords
    int jj = d & 3, lane = (d >> 2) & 63, step = d >> 8;
    int col = lane & 31;
    int off = (lane >> 5)*8 + 2*jj;
    float v0, v1;
    if (step < 32){
        int h = step, c0 = off;
        float mm = s2[h]*INVR_, vv = q2[h]*INVR_ - mm*mm;
        float aa = g2[h] / sqrtf(vv + EPS_);
        v0 = aa * W3[h*512 + c0*COUT_ + col];
        v1 = aa * W3[h*512 + (c0+1)*COUT_ + col];
    } else {
        int c0 = off;
        v0 = b3[c0*COUT_ + col]; v1 = b3[(c0+1)*COUT_ + col];
        #pragma unroll 4
        for (int h = 0; h < H_; ++h){
            float mm = s2[h]*INVR_, vv = q2[h]*INVR_ - mm*mm;
            float aa = g2[h] / sqrtf(vv + EPS_);
            float bb = fmaf(-aa, mm, be2[h]);
            v0 = fmaf(bb, W3[h*512 + c0*COUT_ + col], v0);
            v1 = fmaf(bb, W3[h*512 + (c0+1)*COUT_ + col], v1);
        }
    }
    W3f[d] = pk2(v0, v1);
}

// ---- k_out (FUSED): h1 -> layer2 MFMA swapped (C[ch][row]) -> h2 in regs -> layer3 MFMA -> max ----
// B-frags read from GLOBAL (L1-resident: every wave reads the same 33 KB). Round-9's LDS staging
// capped blocks/CU at 4 (34 KB LDS) and regressed 42->50 us — do not re-stage.
__global__ __launch_bounds__(256,3) void k_out(const float4* __restrict__ xs4g, const int* __restrict__ idx,
                                               const float* __restrict__ W1, const float* __restrict__ b1,
                                               const uint4* __restrict__ W2f, const float* __restrict__ b2p,
                                               const unsigned int* __restrict__ pf16,
                                               const uint4* __restrict__ W3f,
                                               float* __restrict__ out_pre, float* gsum, float* gsq){
    __shared__ float redS[COUT_], redQ[COUT_];
    const int tid = threadIdx.x, lane = tid & 63, w = tid >> 6;
    const int half = lane >> 5, m = lane & 31;
    if (tid < COUT_){ redS[tid] = 0.f; redQ[tid] = 0.f; }
    __syncthreads();

    const int rB = blockIdx.x*256 + w*64;
    int r = blockIdx.x*256 + tid;

    float h1[H_];
    compute_h1v(xs4g, idx, r, W1, b1, h1);
    unsigned int h1p[16];
    #pragma unroll
    for (int i = 0; i < 16; ++i) h1p[i] = pk2(h1[2*i], h1[2*i+1]);

    union { uint4 u4; f16x8 v; } A0, A1;     // W2'^T A-frags (same bits as W2f)
    A0.u4 = W2f[lane];
    A1.u4 = W2f[64 + lane];
    float b2v[16];                            // bias per C-reg: ch = (i&3)+8*(i>>2)+4*half
    #pragma unroll
    for (int i = 0; i < 16; ++i) b2v[i] = b2p[(i&3) + 8*(i>>2) + 4*half];

    const uint4* Wf = W3f + lane;

    #pragma unroll
    for (int t = 0; t < 2; ++t){
        const int src = t*32 + m;
        // B-frags = h1 of data-row t*32+m
        union { unsigned int u[4]; f16x8 v; } B0f, B1f;
        #pragma unroll
        for (int jj = 0; jj < 4; ++jj){
            unsigned int lo = __shfl(h1p[jj],     src, 64);
            unsigned int hi = __shfl(h1p[4 + jj], src, 64);
            B0f.u[jj] = half ? hi : lo;
        }
        #pragma unroll
        for (int jj = 0; jj < 4; ++jj){
            unsigned int lo = __shfl(h1p[8 + jj],  src, 64);
            unsigned int hi = __shfl(h1p[12 + jj], src, 64);
            B1f.u[jj] = half ? hi : lo;
        }
        f32x16 c2;
        #pragma unroll
        for (int i = 0; i < 16; ++i) c2[i] = b2v[i];
        c2 = __builtin_amdgcn_mfma_f32_32x32x16_f16(A0.v, B0f.v, c2, 0, 0, 0);
        c2 = __builtin_amdgcn_mfma_f32_32x32x16_f16(A1.v, B1f.v, c2, 0, 0, 0);

        // relu + pack + half-exchange -> h2p[16] = row (t*32+m)'s 32 channels, f16-packed
        unsigned int h2p[16];
        #pragma unroll
        for (int p = 0; p < 8; ++p){
            float v0 = fmaxf(c2[2*p],   0.0f);
            float v1 = fmaxf(c2[2*p+1], 0.0f);
            unsigned int ow = pk2(v0, v1);
            unsigned int ot = __shfl_xor(ow, 32, 64);
            int a = p >> 1, bb = p & 1;
            h2p[4*a + 2*half     + bb] = ow;
            h2p[4*a + 2*(1-half) + bb] = ot;
        }

        // gp for row t*32+m
        int row = rB + t*32 + m;
        int bb_ = row >> 16;
        int idr = idx[row];
        const uint4* gpp = (const uint4*)(pf16 + ((size_t)bb_*N_ + idr)*8);
        uint4 ga = gpp[0], gb = gpp[1];
        unsigned int gsel[4];
        gsel[0] = half ? gb.x : ga.x;
        gsel[1] = half ? gb.y : ga.y;
        gsel[2] = half ? gb.z : ga.z;
        gsel[3] = half ? gb.w : ga.w;

        f32x16 acc;
        #pragma unroll
        for (int i = 0; i < 16; ++i) acc[i] = 0.f;
        #pragma unroll
        for (int kb = 0; kb < 32; ++kb){
            unsigned int hr = h2p[kb >> 1];
            unsigned int hd = __builtin_amdgcn_perm(hr, hr, (kb & 1) ? 0x03020302u : 0x01000100u);
            union { unsigned int u[4]; f16x8 v; } af;
            #pragma unroll
            for (int jj = 0; jj < 4; ++jj) af.u[jj] = pkmul(hd, gsel[jj]);
            union { uint4 u4; f16x8 v; } bf; bf.u4 = Wf[kb*64];
            acc = __builtin_amdgcn_mfma_f32_32x32x16_f16(af.v, bf.v, acc, 0, 0, 0);
        }
        {   // bias step: A = gp, B = b3'
            union { unsigned int u[4]; f16x8 v; } af;
            #pragma unroll
            for (int jj = 0; jj < 4; ++jj) af.u[jj] = gsel[jj];
            union { uint4 u4; f16x8 v; } bf; bf.u4 = Wf[32*64];
            acc = __builtin_amdgcn_mfma_f32_32x32x16_f16(af.v, bf.v, acc, 0, 0, 0);
        }

        float v = acc[0];
        #pragma unroll
        for (int i = 1; i < 16; ++i) v = fmaxf(v, acc[i]);
        v = fmaxf(v, __shfl_xor(v, 32, 64));
        if (lane < 32){
            int g = blockIdx.x*8 + w*2 + t;
            out_pre[(size_t)g*COUT_ + m] = v;
            atomicAdd(&redS[m], v);
            atomicAdd(&redQ[m], v*v);
        }
    }
    __syncthreads();
    if (tid < COUT_){ atomicAdd(&gsum[tid], redS[tid]); atomicAdd(&gsq[tid], redQ[tid]); }
}

__global__ __launch_bounds__(256) void k_bn(const float* __restrict__ out_pre,
                                            const float* __restrict__ s3, const float* __restrict__ q3,
                                            const float* __restrict__ gbn, const float* __restrict__ bbn,
                                            float* __restrict__ out){
    int i = blockIdx.x*256 + threadIdx.x;
    int o = i & (COUT_-1);
    float mm = s3[o] * INVBN_;
    float vv = q3[o] * INVBN_ - mm*mm;
    float aa = gbn[o] / sqrtf(vv + EPS_);
    out[i] = fmaf(aa, out_pre[i], fmaf(-aa, mm, bbn[o]));
}

extern "C" void kernel_launch(void* const* d_in, const int* in_sizes, int n_in,
                              void* d_out, int out_size, void* d_ws, size_t ws_size,
                              hipStream_t stream){
    const float* xyz    = (const float*)d_in[0];
    const float* points = (const float*)d_in[1];
    const float* W1  = (const float*)d_in[2];
    const float* b1  = (const float*)d_in[3];
    const float* g1  = (const float*)d_in[4];
    const float* be1 = (const float*)d_in[5];
    const float* W2  = (const float*)d_in[6];
    const float* b2  = (const float*)d_in[7];
    const float* g2  = (const float*)d_in[8];
    const float* be2 = (const float*)d_in[9];
    const float* W3  = (const float*)d_in[10];
    const float* b3  = (const float*)d_in[11];
    const float* gbn = (const float*)d_in[12];
    const float* bbn = (const float*)d_in[13];
    float* out = (float*)d_out;

    // ws layout (bytes), ~2.5 MB total
    char* base = (char*)d_ws;
    int*            idx     = (int*)(base + 0);                     // 1,048,576
    float*          out_pre = (float*)(base + 1048576);             // 1,048,576
    unsigned int*   pf16    = (unsigned int*)(base + 2097152);      //    262,144
    unsigned int*   W3f     = (unsigned int*)(base + 2359296);      //     33,792
    unsigned int*   W2f     = (unsigned int*)(base + 2393088);      //      2,048
    float*          b2p     = (float*)(base + 2395136);             //        128
    float*          st      = (float*)(base + 2395264);             //      4,608
    float4*         xs4g    = (float4*)(base + 2399872);            //    131,072
    // st floats: s1s[512] | q1s[512] | s2[32] | q2[32] | s3[32] | q3[32]
    float *s1s=st, *q1s=st+512, *s2=st+1024, *q2=st+1056, *s3=st+1088, *q3=st+1120;

    hipLaunchKernelGGL(k_prep0,   dim3(32),      dim3(256), 0, stream, xyz, xs4g, st);
    hipLaunchKernelGGL(k_knn,     dim3(B_*N_/4), dim3(256), 0, stream, xs4g, W1, b1, idx, s1s, q1s);
    hipLaunchKernelGGL(k_prep2,   dim3(260),     dim3(256), 0, stream, points, s1s, q1s, g1, be1, W2, b2,
                       pf16, W2f, b2p);
    hipLaunchKernelGGL(k_h2stats, dim3(R_/256),  dim3(256), 0, stream, xs4g, idx, W1, b1,
                       (const uint4*)W2f, b2p, s2, q2);
    hipLaunchKernelGGL(k_prep3,   dim3(33),      dim3(256), 0, stream, W3, b3, s2, q2, g2, be2, W3f);
    hipLaunchKernelGGL(k_out,     dim3(R_/256),  dim3(256), 0, stream, xs4g, idx, W1, b1,
                       (const uint4*)W2f, b2p, pf16, (const uint4*)W3f, out_pre, s3, q3);
    hipLaunchKernelGGL(k_bn,      dim3(B_*N_*COUT_/256), dim3(256), 0, stream, out_pre, s3, q3, gbn, bbn, out);
}